// Round 25
// baseline (190.511 us; speedup 1.0000x reference)
//
#include <hip/hip_runtime.h>
#include <hip/hip_fp16.h>

#define N_NODES 20000
#define N_EDGES 640000
#define IN_F    2000
#define KPAD    2048
#define C_OUT   64
#define HC      256   // HEADS * C_OUT
#define NEG     0.2f
#define SCAN_B  79    // ceil(20000/256)

typedef __attribute__((ext_vector_type(4))) float f32x4;
typedef __attribute__((ext_vector_type(8))) short bf16x8;
typedef _Float16 h2 __attribute__((ext_vector_type(2)));    // packed fp16 pair
typedef _Float16 f16x8 __attribute__((ext_vector_type(8))); // MFMA f16 frag

__device__ inline unsigned short f2bf(float f) {
    unsigned u = __float_as_uint(f);
    return (unsigned short)((u + 0x7FFFu + ((u >> 16) & 1u)) >> 16);
}

__device__ inline unsigned cvt_pk_bf16(float lo, float hi) {
    unsigned r;
    asm("v_cvt_pk_bf16_f32 %0, %1, %2" : "=v"(r) : "v"(lo), "v"(hi));
    return r;
}

// async global->LDS DMA, 16B per lane; LDS dest = uniform base + lane*16,
// global src per-lane. Increments vmcnt; __syncthreads() drains it.
__device__ inline void gload16(const float* g, float* l) {
    __builtin_amdgcn_global_load_lds(
        (const __attribute__((address_space(1))) void*)g,
        (__attribute__((address_space(3))) void*)l,
        16, 0, 0);
}

// ------- fused prep: Wpk repack | W_lin fp16 repack | edge histogram -------

__global__ __launch_bounds__(256) void k_prep(
    const float* __restrict__ W_ae, unsigned short* __restrict__ Wpk,
    const float* __restrict__ W_lin, unsigned short* __restrict__ Wt16,
    const int* __restrict__ dst, int* __restrict__ counts) {
    int b = blockIdx.x, t = threadIdx.x;
    if (b < 512) {                 // Wpk = W_ae^T bf16 frag-contig [k>>3][col][k&7]
        int idx = b * 256 + t;     // 64*2048 = 131072
        int n = idx >> 11;
        int k = idx & 2047;
        float v = (k < IN_F) ? W_ae[(size_t)k * C_OUT + n] : 0.f;
        Wpk[(size_t)(k >> 3) * 512 + n * 8 + (k & 7)] = f2bf(v);
    } else if (b < 576) {          // Wt16 = W_lin^T fp16
        int idx = (b - 512) * 256 + t;   // 64*256 = 16384
        int col = idx >> 8;
        int k = idx & 255;
        _Float16 v = (_Float16)W_lin[(size_t)k * C_OUT + col];
        Wt16[(size_t)col * HC + k] = __builtin_bit_cast(unsigned short, v);
    } else {                       // hist
        int e = (b - 576) * 256 + t;
        if (e < N_EDGES) atomicAdd(&counts[dst[e]], 1);
    }
}

// ---------------- scan (3 small kernels) ----------------

__global__ void k_scan1(const int* __restrict__ counts, int* __restrict__ bsum) {
    int t = threadIdx.x, b = blockIdx.x;
    int i = b * 256 + t;
    int v = (i < N_NODES) ? counts[i] : 0;
    int s = v;
    #pragma unroll
    for (int d = 1; d < 64; d <<= 1) s += __shfl_xor(s, d, 64);
    __shared__ int ws[4];
    if ((t & 63) == 0) ws[t >> 6] = s;
    __syncthreads();
    if (t == 0) bsum[b] = ws[0] + ws[1] + ws[2] + ws[3];
}

__global__ void k_scan2(const int* __restrict__ bsum, int* __restrict__ bbase,
                        int* __restrict__ offsets) {
    int lane = threadIdx.x;   // 64 threads
    int v0 = (lane < SCAN_B) ? bsum[lane] : 0;
    int v1 = (64 + lane < SCAN_B) ? bsum[64 + lane] : 0;
    int s0 = v0;
    #pragma unroll
    for (int d = 1; d < 64; d <<= 1) { int t = __shfl_up(s0, d, 64); if (lane >= d) s0 += t; }
    int tot0 = __shfl(s0, 63, 64);
    int s1 = v1;
    #pragma unroll
    for (int d = 1; d < 64; d <<= 1) { int t = __shfl_up(s1, d, 64); if (lane >= d) s1 += t; }
    int tot1 = __shfl(s1, 63, 64);
    if (lane < SCAN_B) bbase[lane] = s0 - v0;
    if (64 + lane < SCAN_B) bbase[64 + lane] = tot0 + s1 - v1;
    if (lane == 0) offsets[N_NODES] = tot0 + tot1;
}

__global__ void k_scan3(const int* __restrict__ counts, const int* __restrict__ bbase,
                        int* __restrict__ offsets, int* __restrict__ cursor) {
    int t = threadIdx.x, b = blockIdx.x;
    int lane = t & 63, wid = t >> 6;
    int i = b * 256 + t;
    int v = (i < N_NODES) ? counts[i] : 0;
    int s = v;
    #pragma unroll
    for (int d = 1; d < 64; d <<= 1) { int u = __shfl_up(s, d, 64); if (lane >= d) s += u; }
    __shared__ int ws[4];
    if (lane == 63) ws[wid] = s;
    __syncthreads();
    int wb = 0;
    #pragma unroll
    for (int w = 0; w < 3; ++w) if (w < wid) wb += ws[w];
    int excl = bbase[b] + wb + (s - v);
    if (i < N_NODES) { offsets[i] = excl; cursor[i] = excl; }
}

// -------- fused: h = x@W_ae+b (bf16 MFMA, ASYNC global_load_lds A-staging) |
//                 scatter (odd blocks), interleaved by parity --------
// gemm block: 16 rows x 64 cols, 8 waves (4 col-tiles x 2 k-halves).
// A staged fp32 via global_load_lds width=16 (DMA; many requests in flight,
// independent of wave ILP). LDS write is linear, so the bank swizzle is done
// by pre-swizzling the per-lane GLOBAL source slot (slot ^= row&7) and
// XOR-ing the same on the ds_read side (rule #21). fp32->bf16 at read time.
// Tail k>=2000: source slot clamped (finite garbage x zero-padded Wpk = 0).

__global__ __launch_bounds__(512) void k_gemm_sc(
    const float* __restrict__ x, const unsigned short* __restrict__ Wpk,
    const float* __restrict__ b, float* __restrict__ h,
    const int* __restrict__ src, const int* __restrict__ dst,
    int* __restrict__ cursor, int* __restrict__ ssrc) {
    if (blockIdx.x & 1) {          // scatter: 1250 blocks x 512 thr = 640000
        int e = (blockIdx.x >> 1) * 512 + threadIdx.x;
        if (e < N_EDGES) {
            int d = dst[e];
            int p = atomicAdd(&cursor[d], 1);
            ssrc[p] = src[e];
        }
        return;
    }
    __shared__ float Asw[16][512];              // 32 KB fp32 tile (swizzled slots)
    __shared__ float red[4][16][17];            // k-half combine, +1 pad
    int t = threadIdx.x;
    int lane = t & 63, w = t >> 6;
    int row0 = (blockIdx.x >> 1) * 16;  // 1250*16 = 20000 exact
    int r = lane & 15, kc = lane >> 4;
    int ct = w & 3;                // col tile: cols ct*16..+15
    int kh = w >> 2;               // k-half 0/1 (256 floats each)
    int q = r & 7;
    f32x4 acc = {0.f, 0.f, 0.f, 0.f};

    for (int it = 0; it < 4; ++it) {
        // ---- stage: wave w DMAs rows 2w,2w+1 (4 x 1KB instructions) ----
        #pragma unroll
        for (int seg = 0; seg < 4; ++seg) {
            int row = 2 * w + (seg >> 1);
            int s2  = seg & 1;
            int j   = s2 * 64 + lane;           // LDS slot within row (0..127)
            int sj  = j ^ (row & 7);            // pre-swizzled source slot
            int gsl = it * 128 + sj;            // global 16B slot (500 valid)
            gsl = gsl <= 499 ? gsl : 499;       // clamp: garbage ok (B zero-padded)
            gload16(x + (size_t)(row0 + row) * IN_F + gsl * 4,
                    &Asw[row][s2 * 256]);       // uniform LDS base per instr
        }
        __syncthreads();                        // drains vmcnt incl. DMA
        // ---- compute: wave (ct, kh): 8 x K32 MFMA over its k-half ----
        #pragma unroll
        for (int s = 0; s < 8; ++s) {
            int cki = kh * 32 + s * 4 + kc;     // in-iter chunk 0..63 (8 floats)
            int j0 = (2 * cki) ^ q;             // swizzled LDS slots of the chunk
            int j1 = (2 * cki + 1) ^ q;
            f32x4 a0 = *(f32x4*)&Asw[r][j0 * 4];
            f32x4 a1 = *(f32x4*)&Asw[r][j1 * 4];
            uint4 uu;
            uu.x = cvt_pk_bf16(a0[0], a0[1]);
            uu.y = cvt_pk_bf16(a0[2], a0[3]);
            uu.z = cvt_pk_bf16(a1[0], a1[1]);
            uu.w = cvt_pk_bf16(a1[2], a1[3]);
            bf16x8 af = __builtin_bit_cast(bf16x8, uu);
            int gch = it * 64 + cki;            // global k chunk (Wpk zero for >=250)
            bf16x8 bf = *(const bf16x8*)&Wpk[(size_t)gch * 512 + (ct * 16 + r) * 8];
            acc = __builtin_amdgcn_mfma_f32_16x16x32_bf16(af, bf, acc, 0, 0, 0);
        }
        __syncthreads();
    }

    // ---- combine the 2 k-halves, bias, store ----
    int ci = (lane >> 4) * 4, cj = lane & 15;
    if (kh == 1) {
        #pragma unroll
        for (int rr = 0; rr < 4; ++rr) red[ct][ci + rr][cj] = acc[rr];
    }
    __syncthreads();
    if (kh == 0) {
        float bb = b[ct * 16 + cj];
        #pragma unroll
        for (int rr = 0; rr < 4; ++rr) {
            float s = acc[rr] + red[ct][ci + rr][cj] + bb;
            h[(size_t)(row0 + ci + rr) * C_OUT + ct * 16 + cj] = s;
        }
    }
}

// ---------------- xl (fp16, node-major) | xr (fp32) = h @ [Wl|Wr] + [bl|br] --

__global__ __launch_bounds__(256) void k_xlxr2(
    const float* __restrict__ h, const float* __restrict__ Wl, const float* __restrict__ bl,
    const float* __restrict__ Wr, const float* __restrict__ br,
    unsigned short* __restrict__ xlh, float* __restrict__ xr) {
    __shared__ float hs[64][68];
    __shared__ float Ws[64][128];
    int t = threadIdx.x;
    int mb = blockIdx.x >> 2, nb = blockIdx.x & 3;
    int node0 = mb * 64;
    const float* Wsrc = (nb < 2) ? (Wl + nb * 128) : (Wr + (nb - 2) * 128);
    const float* bsrc = (nb < 2) ? (bl + nb * 128) : (br + (nb - 2) * 128);

    {
        int row = t >> 2, q = t & 3;
        int gnode = node0 + row; if (gnode >= N_NODES) gnode = N_NODES - 1;
        const float4* src = (const float4*)&h[(size_t)gnode * C_OUT + q * 16];
        *(float4*)&hs[row][q * 16 + 0]  = src[0];
        *(float4*)&hs[row][q * 16 + 4]  = src[1];
        *(float4*)&hs[row][q * 16 + 8]  = src[2];
        *(float4*)&hs[row][q * 16 + 12] = src[3];
    }
    {
        #pragma unroll
        for (int i = 0; i < 8; ++i) {
            int f = t + i * 256;
            int k = f >> 5, c4 = (f & 31) << 2;
            *(float4*)&Ws[k][c4] = *(const float4*)&Wsrc[(size_t)k * HC + c4];
        }
    }
    __syncthreads();

    int tr = t >> 5;
    int tc = t & 31;
    float4 acc[8];
    float4 bv = *(const float4*)&bsrc[tc * 4];
    #pragma unroll
    for (int r = 0; r < 8; ++r) acc[r] = bv;

    for (int k4 = 0; k4 < 64; k4 += 4) {
        float4 w0 = *(float4*)&Ws[k4 + 0][tc * 4];
        float4 w1 = *(float4*)&Ws[k4 + 1][tc * 4];
        float4 w2 = *(float4*)&Ws[k4 + 2][tc * 4];
        float4 w3 = *(float4*)&Ws[k4 + 3][tc * 4];
        #pragma unroll
        for (int r = 0; r < 8; ++r) {
            float4 a = *(float4*)&hs[tr * 8 + r][k4];
            acc[r].x += a.x * w0.x + a.y * w1.x + a.z * w2.x + a.w * w3.x;
            acc[r].y += a.x * w0.y + a.y * w1.y + a.z * w2.y + a.w * w3.y;
            acc[r].z += a.x * w0.z + a.y * w1.z + a.z * w2.z + a.w * w3.z;
            acc[r].w += a.x * w0.w + a.y * w1.w + a.z * w2.w + a.w * w3.w;
        }
    }
    #pragma unroll
    for (int r = 0; r < 8; ++r) {
        int gnode = node0 + tr * 8 + r;
        if (gnode < N_NODES) {
            if (nb < 2) {
                h2 lo = { (_Float16)acc[r].x, (_Float16)acc[r].y };
                h2 hi = { (_Float16)acc[r].z, (_Float16)acc[r].w };
                uint2 o = { __builtin_bit_cast(unsigned, lo),
                            __builtin_bit_cast(unsigned, hi) };
                *(uint2*)&xlh[(size_t)gnode * HC + nb * 128 + tc * 4] = o;
            } else {
                *(float4*)&xr[(size_t)gnode * HC + (nb - 2) * 128 + tc * 4] = acc[r];
            }
        }
    }
}

// ---------------- attention: 4 indep waves/block, 2-deep pipeline ----------------

__global__ __launch_bounds__(256) void k_attn(
    const unsigned short* __restrict__ xlh, const float* __restrict__ xr,
    const int* __restrict__ offsets, const int* __restrict__ ssrc,
    const float* __restrict__ att, const float* __restrict__ b_conv,
    unsigned short* __restrict__ ovh) {
    int wid = threadIdx.x >> 6, lane = threadIdx.x & 63;
    int node = blockIdx.x * 4 + wid;     // 5000*4 = 20000 exact
    int sub = lane >> 4;     // edge slot 0..3
    int sl  = lane & 15;     // channel group
    int c0  = sl * 16;

    const h2 z2  = { (_Float16)0.f, (_Float16)0.f };
    const h2 ns2 = { (_Float16)NEG, (_Float16)NEG };

    h2 xr2[8], at2[8];
    #pragma unroll
    for (int i = 0; i < 4; ++i) {
        float4 t4 = *(const float4*)&xr[(size_t)node * HC + c0 + i * 4];
        xr2[i*2+0] = h2{ (_Float16)t4.x, (_Float16)t4.y };
        xr2[i*2+1] = h2{ (_Float16)t4.z, (_Float16)t4.w };
        float4 a4 = *(const float4*)&att[c0 + i * 4];
        at2[i*2+0] = h2{ (_Float16)a4.x, (_Float16)a4.y };
        at2[i*2+1] = h2{ (_Float16)a4.z, (_Float16)a4.w };
    }
    h2 acc2[8];
    #pragma unroll
    for (int i = 0; i < 8; ++i) acc2[i] = z2;
    float denom = 0.f;

    auto load_edge = [&](int j, uint4& w0, uint4& w1) {
        const uint4* rp = (const uint4*)&xlh[(size_t)j * HC + c0];
        w0 = rp[0]; w1 = rp[1];
    };
    auto compute_edge = [&](uint4 w0, uint4 w1, bool valid) {
        h2 x2[8];
        x2[0] = __builtin_bit_cast(h2, w0.x); x2[1] = __builtin_bit_cast(h2, w0.y);
        x2[2] = __builtin_bit_cast(h2, w0.z); x2[3] = __builtin_bit_cast(h2, w0.w);
        x2[4] = __builtin_bit_cast(h2, w1.x); x2[5] = __builtin_bit_cast(h2, w1.y);
        x2[6] = __builtin_bit_cast(h2, w1.z); x2[7] = __builtin_bit_cast(h2, w1.w);
        h2 p2 = z2;
        #pragma unroll
        for (int i = 0; i < 8; ++i) {
            h2 g  = x2[i] + xr2[i];
            h2 gs = g * ns2;
            g = __builtin_elementwise_max(g, gs);   // leaky: max(g, 0.2g), exact
            p2 += g * at2[i];
        }
        float p = (float)p2.x + (float)p2.y;
        p += __shfl_xor(p, 1); p += __shfl_xor(p, 2);   // 4 lanes = one head
        float ex = valid ? __expf(p) : 0.f;             // logits O(1): no max shift
        denom += ex;
        h2 e2 = { (_Float16)ex, (_Float16)ex };
        #pragma unroll
        for (int i = 0; i < 8; ++i) acc2[i] += e2 * x2[i];
    };

    {   // self loop (counted once, slot 0)
        uint4 s0v, s1v;
        load_edge(node, s0v, s1v);
        compute_edge(s0v, s1v, sub == 0);
    }

    int s0 = offsets[node], s1 = offsets[node + 1];
    for (int base = s0; base < s1; base += 64) {
        int rem = s1 - base;
        int cnt = rem < 64 ? rem : 64;
        int jv = (base + lane < s1) ? ssrc[base + lane] : 0;
        int niter = (cnt + 3) >> 2;
        uint4 a0, a1, b0, b1;
        int jA = __shfl(jv, sub, 64);
        load_edge(jA, a0, a1);
        for (int it = 0; it < niter; it += 2) {
            int eB = ((it + 1) << 2) + sub;
            int jB = __shfl(jv, eB & 63, 64);
            load_edge(jB, b0, b1);                    // prefetch B under A's compute
            compute_edge(a0, a1, ((it << 2) + sub) < cnt);
            int eA2 = ((it + 2) << 2) + sub;
            int jA2 = __shfl(jv, eA2 & 63, 64);
            load_edge(jA2, a0, a1);                   // prefetch next A under B
            compute_edge(b0, b1, eB < cnt);
        }
    }

    // unpack to fp32, reduce over the 4 edge slots
    float accf[16];
    #pragma unroll
    for (int i = 0; i < 8; ++i) {
        accf[2*i]   = (float)acc2[i].x;
        accf[2*i+1] = (float)acc2[i].y;
    }
    #pragma unroll
    for (int i = 0; i < 16; ++i) {
        accf[i] += __shfl_xor(accf[i], 16);
        accf[i] += __shfl_xor(accf[i], 32);
    }
    denom += __shfl_xor(denom, 16);
    denom += __shfl_xor(denom, 32);

    float inv = 1.f / denom;
    if (sub == 0) {   // 16 lanes write 16 fp16 each
        float bcf[16];
        #pragma unroll
        for (int i = 0; i < 4; ++i) {
            float4 bc = *(const float4*)&b_conv[c0 + i * 4];
            bcf[i*4+0] = bc.x; bcf[i*4+1] = bc.y; bcf[i*4+2] = bc.z; bcf[i*4+3] = bc.w;
        }
        unsigned ww[8];
        #pragma unroll
        for (int i = 0; i < 8; ++i) {
            h2 p = { (_Float16)(accf[2*i]   * inv + bcf[2*i]),
                     (_Float16)(accf[2*i+1] * inv + bcf[2*i+1]) };
            ww[i] = __builtin_bit_cast(unsigned, p);
        }
        uint4 o0 = { ww[0], ww[1], ww[2], ww[3] };
        uint4 o1 = { ww[4], ww[5], ww[6], ww[7] };
        *(uint4*)&ovh[(size_t)node * HC + c0]     = o0;
        *(uint4*)&ovh[(size_t)node * HC + c0 + 8] = o1;
    }
}

// ---------------- post: relu(ov @ W_lin + b_lin) + h -> LayerNorm -> out -----

__global__ __launch_bounds__(256) void k_post(
    const unsigned short* __restrict__ ovh, const unsigned short* __restrict__ Wt16,
    const float* __restrict__ b_lin, const float* __restrict__ hbuf,
    const float* __restrict__ ln_w, const float* __restrict__ ln_b,
    float* __restrict__ out) {
    int t = threadIdx.x;
    int lane = t & 63, w = t >> 6;
    int node0 = blockIdx.x * 64 + w * 16;
    int r = lane & 15, kc = lane >> 4;
    int noder = node0 + r;
    int nodec = noder < N_NODES ? noder : N_NODES - 1;

    f32x4 acc[4] = {{0,0,0,0},{0,0,0,0},{0,0,0,0},{0,0,0,0}};
    #pragma unroll
    for (int k0 = 0; k0 < HC; k0 += 32) {
        int kb = k0 + kc * 8;
        f16x8 af = *(const f16x8*)&ovh[(size_t)nodec * HC + kb];
        #pragma unroll
        for (int cb = 0; cb < 4; ++cb) {
            f16x8 bf = *(const f16x8*)&Wt16[(size_t)(cb * 16 + r) * HC + kb];
            acc[cb] = __builtin_amdgcn_mfma_f32_16x16x32_f16(af, bf, acc[cb], 0, 0, 0);
        }
    }

    int ci = (lane >> 4) * 4, cj = lane & 15;
    #pragma unroll
    for (int rr = 0; rr < 4; ++rr) {
        int grow = node0 + ci + rr;
        int growc = grow < N_NODES ? grow : N_NODES - 1;
        float y[4];
        float ssum = 0.f;
        #pragma unroll
        for (int cb = 0; cb < 4; ++cb) {
            int col = cb * 16 + cj;
            float a = acc[cb][rr] + b_lin[col];
            a = a > 0.f ? a : 0.f;
            float yy = a + hbuf[(size_t)growc * C_OUT + col];
            y[cb] = yy;
            ssum += yy;
        }
        ssum += __shfl_xor(ssum, 1); ssum += __shfl_xor(ssum, 2);
        ssum += __shfl_xor(ssum, 4); ssum += __shfl_xor(ssum, 8);
        float m = ssum * (1.f / 64.f);
        float vs = 0.f;
        #pragma unroll
        for (int cb = 0; cb < 4; ++cb) { float d = y[cb] - m; vs += d * d; }
        vs += __shfl_xor(vs, 1); vs += __shfl_xor(vs, 2);
        vs += __shfl_xor(vs, 4); vs += __shfl_xor(vs, 8);
        float rinv = rsqrtf(vs * (1.f / 64.f) + 1e-12f);
        if (grow < N_NODES) {
            #pragma unroll
            for (int cb = 0; cb < 4; ++cb) {
                int col = cb * 16 + cj;
                out[(size_t)grow * C_OUT + col] =
                    ln_w[col] * (y[cb] - m) * rinv + ln_b[col];
            }
        }
    }
}

// ---------------- launch ----------------

extern "C" void kernel_launch(void* const* d_in, const int* in_sizes, int n_in,
                              void* d_out, int out_size, void* d_ws, size_t ws_size,
                              hipStream_t stream) {
    const float* x     = (const float*)d_in[0];
    const int*   ei    = (const int*)  d_in[1];
    const float* W_ae  = (const float*)d_in[2];
    const float* b_ae  = (const float*)d_in[3];
    const float* Wl    = (const float*)d_in[4];
    const float* bl    = (const float*)d_in[5];
    const float* Wr    = (const float*)d_in[6];
    const float* br    = (const float*)d_in[7];
    const float* att   = (const float*)d_in[8];
    const float* b_conv= (const float*)d_in[9];
    const float* W_lin = (const float*)d_in[10];
    const float* b_lin = (const float*)d_in[11];
    const float* ln_w  = (const float*)d_in[12];
    const float* ln_b  = (const float*)d_in[13];
    float* out = (float*)d_out;
    const int* src = ei;
    const int* dst = ei + N_EDGES;

    char* ws = (char*)d_ws;
    size_t off = 0;
    auto alloc = [&](size_t bytes) {
        void* p = ws + off;
        off = (off + bytes + 255) & ~(size_t)255;
        return p;
    };
    float* h       = (float*)alloc((size_t)N_NODES * C_OUT * 4);
    unsigned short* xlh = (unsigned short*)alloc((size_t)N_NODES * HC * 2);
    float* xr      = (float*)alloc((size_t)N_NODES * HC * 4);
    unsigned short* ovh = (unsigned short*)alloc((size_t)N_NODES * HC * 2);
    int*   counts  = (int*)  alloc((size_t)N_NODES * 4);
    int*   offsets = (int*)  alloc((size_t)(N_NODES + 1) * 4);
    int*   cursor  = (int*)  alloc((size_t)N_NODES * 4);
    int*   ssrc    = (int*)  alloc((size_t)N_EDGES * 4);
    unsigned short* Wpk  = (unsigned short*)alloc((size_t)C_OUT * KPAD * 2);
    unsigned short* Wt16 = (unsigned short*)alloc((size_t)C_OUT * HC * 2);
    int*   bsum    = (int*)  alloc((size_t)SCAN_B * 4);
    int*   bbase   = (int*)  alloc((size_t)SCAN_B * 4);

    (void)hipMemsetAsync(counts, 0, (size_t)N_NODES * 4, stream);
    k_prep   <<<576 + (N_EDGES + 255) / 256, 256, 0, stream>>>(W_ae, Wpk, W_lin, Wt16,
                                                               dst, counts);
    k_scan1  <<<SCAN_B, 256, 0, stream>>>(counts, bsum);
    k_scan2  <<<1, 64, 0, stream>>>(bsum, bbase, offsets);
    k_scan3  <<<SCAN_B, 256, 0, stream>>>(counts, bbase, offsets, cursor);
    k_gemm_sc<<<2500, 512, 0, stream>>>(x, Wpk, b_ae, h, src, dst, cursor, ssrc);
    k_xlxr2  <<<((N_NODES + 63) / 64) * 4, 256, 0, stream>>>(h, Wl, bl, Wr, br, xlh, xr);
    k_attn   <<<N_NODES / 4, 256, 0, stream>>>(xlh, xr, offsets, ssrc, att, b_conv, ovh);
    k_post   <<<(N_NODES + 63) / 64, 256, 0, stream>>>(ovh, Wt16, b_lin, h,
                                                       ln_w, ln_b, out);
}

// Round 26
// 176.862 us; speedup vs baseline: 1.0772x; 1.0772x over previous
//
#include <hip/hip_runtime.h>
#include <hip/hip_fp16.h>

#define N_NODES 20000
#define N_EDGES 640000
#define IN_F    2000
#define KPAD    2048
#define C_OUT   64
#define HC      256   // HEADS * C_OUT
#define NEG     0.2f
#define SCAN_B  79    // ceil(20000/256)

typedef __attribute__((ext_vector_type(4))) float f32x4;
typedef __attribute__((ext_vector_type(8))) short bf16x8;
typedef _Float16 h2 __attribute__((ext_vector_type(2)));    // packed fp16 pair
typedef _Float16 f16x8 __attribute__((ext_vector_type(8))); // MFMA f16 frag

__device__ inline unsigned short f2bf(float f) {
    unsigned u = __float_as_uint(f);
    return (unsigned short)((u + 0x7FFFu + ((u >> 16) & 1u)) >> 16);
}

__device__ inline unsigned cvt_pk_bf16(float lo, float hi) {
    unsigned r;
    asm("v_cvt_pk_bf16_f32 %0, %1, %2" : "=v"(r) : "v"(lo), "v"(hi));
    return r;
}

// ------- fused prep: Wpk repack | W_lin fp16 repack | edge histogram -------

__global__ __launch_bounds__(256) void k_prep(
    const float* __restrict__ W_ae, unsigned short* __restrict__ Wpk,
    const float* __restrict__ W_lin, unsigned short* __restrict__ Wt16,
    const int* __restrict__ dst, int* __restrict__ counts) {
    int b = blockIdx.x, t = threadIdx.x;
    if (b < 512) {                 // Wpk = W_ae^T bf16 frag-contig [k>>3][col][k&7]
        int idx = b * 256 + t;     // 64*2048 = 131072
        int n = idx >> 11;
        int k = idx & 2047;
        float v = (k < IN_F) ? W_ae[(size_t)k * C_OUT + n] : 0.f;
        Wpk[(size_t)(k >> 3) * 512 + n * 8 + (k & 7)] = f2bf(v);
    } else if (b < 576) {          // Wt16 = W_lin^T fp16
        int idx = (b - 512) * 256 + t;   // 64*256 = 16384
        int col = idx >> 8;
        int k = idx & 255;
        _Float16 v = (_Float16)W_lin[(size_t)k * C_OUT + col];
        Wt16[(size_t)col * HC + k] = __builtin_bit_cast(unsigned short, v);
    } else {                       // hist
        int e = (b - 576) * 256 + t;
        if (e < N_EDGES) atomicAdd(&counts[dst[e]], 1);
    }
}

// ---------------- scan (3 small kernels) ----------------

__global__ void k_scan1(const int* __restrict__ counts, int* __restrict__ bsum) {
    int t = threadIdx.x, b = blockIdx.x;
    int i = b * 256 + t;
    int v = (i < N_NODES) ? counts[i] : 0;
    int s = v;
    #pragma unroll
    for (int d = 1; d < 64; d <<= 1) s += __shfl_xor(s, d, 64);
    __shared__ int ws[4];
    if ((t & 63) == 0) ws[t >> 6] = s;
    __syncthreads();
    if (t == 0) bsum[b] = ws[0] + ws[1] + ws[2] + ws[3];
}

__global__ void k_scan2(const int* __restrict__ bsum, int* __restrict__ bbase,
                        int* __restrict__ offsets) {
    int lane = threadIdx.x;   // 64 threads
    int v0 = (lane < SCAN_B) ? bsum[lane] : 0;
    int v1 = (64 + lane < SCAN_B) ? bsum[64 + lane] : 0;
    int s0 = v0;
    #pragma unroll
    for (int d = 1; d < 64; d <<= 1) { int t = __shfl_up(s0, d, 64); if (lane >= d) s0 += t; }
    int tot0 = __shfl(s0, 63, 64);
    int s1 = v1;
    #pragma unroll
    for (int d = 1; d < 64; d <<= 1) { int t = __shfl_up(s1, d, 64); if (lane >= d) s1 += t; }
    int tot1 = __shfl(s1, 63, 64);
    if (lane < SCAN_B) bbase[lane] = s0 - v0;
    if (64 + lane < SCAN_B) bbase[64 + lane] = tot0 + s1 - v1;
    if (lane == 0) offsets[N_NODES] = tot0 + tot1;
}

__global__ void k_scan3(const int* __restrict__ counts, const int* __restrict__ bbase,
                        int* __restrict__ offsets, int* __restrict__ cursor) {
    int t = threadIdx.x, b = blockIdx.x;
    int lane = t & 63, wid = t >> 6;
    int i = b * 256 + t;
    int v = (i < N_NODES) ? counts[i] : 0;
    int s = v;
    #pragma unroll
    for (int d = 1; d < 64; d <<= 1) { int u = __shfl_up(s, d, 64); if (lane >= d) s += u; }
    __shared__ int ws[4];
    if (lane == 63) ws[wid] = s;
    __syncthreads();
    int wb = 0;
    #pragma unroll
    for (int w = 0; w < 3; ++w) if (w < wid) wb += ws[w];
    int excl = bbase[b] + wb + (s - v);
    if (i < N_NODES) { offsets[i] = excl; cursor[i] = excl; }
}

// -------- fused: h = x@W_ae+b (bf16 MFMA, LDS-staged) | scatter --------
// INTERLEAVED roles by block parity: odd = scatter, even = gemm, so scatter
// executes concurrently under the gemm blocks' memory-latency stalls.

__global__ __launch_bounds__(512) void k_gemm_sc(
    const float* __restrict__ x, const unsigned short* __restrict__ Wpk,
    const float* __restrict__ b, float* __restrict__ h,
    const int* __restrict__ src, const int* __restrict__ dst,
    int* __restrict__ cursor, int* __restrict__ ssrc) {
    if (blockIdx.x & 1) {          // scatter: 1250 blocks x 512 thr = 640000
        int e = (blockIdx.x >> 1) * 512 + threadIdx.x;
        if (e < N_EDGES) {
            int d = dst[e];
            int p = atomicAdd(&cursor[d], 1);
            ssrc[p] = src[e];
        }
        return;
    }
    __shared__ unsigned short Asw[16][64][8];   // 16 KB bf16 tile
    __shared__ float red[4][16][17];            // k-half combine, +1 pad
    int t = threadIdx.x;
    int lane = t & 63, w = t >> 6;
    int row0 = (blockIdx.x >> 1) * 16;  // 1250*16 = 20000 exact
    int r = lane & 15, kc = lane >> 4;
    int ct = w & 3;                // col tile: cols ct*16..+15
    int kh = w >> 2;               // k-half 0/1 (256 floats each)
    int srow = t >> 5;             // staging row 0..15 (32 thr/row)
    int sj   = t & 31;
    const float* xrow = x + (size_t)(row0 + srow) * IN_F;
    f32x4 acc = {0.f, 0.f, 0.f, 0.f};

    for (int it = 0; it < 4; ++it) {
        // ---- stage: 16 rows x 512 floats -> bf16 LDS (coalesced reads) ----
        #pragma unroll
        for (int p = 0; p < 4; ++p) {
            int f  = p * 128 + sj * 4;        // 0..511 within row-chunk
            int kg = it * 512 + f;            // global k (2000 % 4 == 0)
            float4 v = {0.f, 0.f, 0.f, 0.f};
            if (kg < IN_F) v = *(const float4*)&xrow[kg];
            unsigned lo = cvt_pk_bf16(v.x, v.y);
            unsigned hi = cvt_pk_bf16(v.z, v.w);
            int c = (f >> 3) ^ srow;          // XOR swizzle (bijective, 16|64)
            int o = f & 7;                    // 0 or 4
            *(unsigned*)&Asw[srow][c][o]     = lo;
            *(unsigned*)&Asw[srow][c][o + 2] = hi;
        }
        __syncthreads();
        // ---- compute: wave (ct, kh): 8 x K32 MFMA over its k-half ----
        int cb0 = kh * 32;                    // chunk base (32 chunks = 256 k)
        #pragma unroll
        for (int s = 0; s < 8; ++s) {
            int cki = cb0 + s * 4 + kc;       // in-row chunk 0..63
            bf16x8 af = *(bf16x8*)&Asw[r][cki ^ r][0];
            int gch = it * 64 + cki;          // global k chunk
            bf16x8 bf = *(const bf16x8*)&Wpk[(size_t)gch * 512 + (ct * 16 + r) * 8];
            acc = __builtin_amdgcn_mfma_f32_16x16x32_bf16(af, bf, acc, 0, 0, 0);
        }
        __syncthreads();
    }

    // ---- combine the 2 k-halves, bias, store ----
    int ci = (lane >> 4) * 4, cj = lane & 15;
    if (kh == 1) {
        #pragma unroll
        for (int rr = 0; rr < 4; ++rr) red[ct][ci + rr][cj] = acc[rr];
    }
    __syncthreads();
    if (kh == 0) {
        float bb = b[ct * 16 + cj];
        #pragma unroll
        for (int rr = 0; rr < 4; ++rr) {
            float s = acc[rr] + red[ct][ci + rr][cj] + bb;
            h[(size_t)(row0 + ci + rr) * C_OUT + ct * 16 + cj] = s;
        }
    }
}

// ---------------- xl (fp16, node-major) | xr (fp32) = h @ [Wl|Wr] + [bl|br] --

__global__ __launch_bounds__(256) void k_xlxr2(
    const float* __restrict__ h, const float* __restrict__ Wl, const float* __restrict__ bl,
    const float* __restrict__ Wr, const float* __restrict__ br,
    unsigned short* __restrict__ xlh, float* __restrict__ xr) {
    __shared__ float hs[64][68];
    __shared__ float Ws[64][128];
    int t = threadIdx.x;
    int mb = blockIdx.x >> 2, nb = blockIdx.x & 3;
    int node0 = mb * 64;
    const float* Wsrc = (nb < 2) ? (Wl + nb * 128) : (Wr + (nb - 2) * 128);
    const float* bsrc = (nb < 2) ? (bl + nb * 128) : (br + (nb - 2) * 128);

    {
        int row = t >> 2, q = t & 3;
        int gnode = node0 + row; if (gnode >= N_NODES) gnode = N_NODES - 1;
        const float4* src = (const float4*)&h[(size_t)gnode * C_OUT + q * 16];
        *(float4*)&hs[row][q * 16 + 0]  = src[0];
        *(float4*)&hs[row][q * 16 + 4]  = src[1];
        *(float4*)&hs[row][q * 16 + 8]  = src[2];
        *(float4*)&hs[row][q * 16 + 12] = src[3];
    }
    {
        #pragma unroll
        for (int i = 0; i < 8; ++i) {
            int f = t + i * 256;
            int k = f >> 5, c4 = (f & 31) << 2;
            *(float4*)&Ws[k][c4] = *(const float4*)&Wsrc[(size_t)k * HC + c4];
        }
    }
    __syncthreads();

    int tr = t >> 5;
    int tc = t & 31;
    float4 acc[8];
    float4 bv = *(const float4*)&bsrc[tc * 4];
    #pragma unroll
    for (int r = 0; r < 8; ++r) acc[r] = bv;

    for (int k4 = 0; k4 < 64; k4 += 4) {
        float4 w0 = *(float4*)&Ws[k4 + 0][tc * 4];
        float4 w1 = *(float4*)&Ws[k4 + 1][tc * 4];
        float4 w2 = *(float4*)&Ws[k4 + 2][tc * 4];
        float4 w3 = *(float4*)&Ws[k4 + 3][tc * 4];
        #pragma unroll
        for (int r = 0; r < 8; ++r) {
            float4 a = *(float4*)&hs[tr * 8 + r][k4];
            acc[r].x += a.x * w0.x + a.y * w1.x + a.z * w2.x + a.w * w3.x;
            acc[r].y += a.x * w0.y + a.y * w1.y + a.z * w2.y + a.w * w3.y;
            acc[r].z += a.x * w0.z + a.y * w1.z + a.z * w2.z + a.w * w3.z;
            acc[r].w += a.x * w0.w + a.y * w1.w + a.z * w2.w + a.w * w3.w;
        }
    }
    #pragma unroll
    for (int r = 0; r < 8; ++r) {
        int gnode = node0 + tr * 8 + r;
        if (gnode < N_NODES) {
            if (nb < 2) {
                h2 lo = { (_Float16)acc[r].x, (_Float16)acc[r].y };
                h2 hi = { (_Float16)acc[r].z, (_Float16)acc[r].w };
                uint2 o = { __builtin_bit_cast(unsigned, lo),
                            __builtin_bit_cast(unsigned, hi) };
                *(uint2*)&xlh[(size_t)gnode * HC + nb * 128 + tc * 4] = o;
            } else {
                *(float4*)&xr[(size_t)gnode * HC + (nb - 2) * 128 + tc * 4] = acc[r];
            }
        }
    }
}

// ---------------- attention: 4 indep waves/block, 2-deep pipeline ----------------

__global__ __launch_bounds__(256) void k_attn(
    const unsigned short* __restrict__ xlh, const float* __restrict__ xr,
    const int* __restrict__ offsets, const int* __restrict__ ssrc,
    const float* __restrict__ att, const float* __restrict__ b_conv,
    unsigned short* __restrict__ ovh) {
    int wid = threadIdx.x >> 6, lane = threadIdx.x & 63;
    int node = blockIdx.x * 4 + wid;     // 5000*4 = 20000 exact
    int sub = lane >> 4;     // edge slot 0..3
    int sl  = lane & 15;     // channel group
    int c0  = sl * 16;

    const h2 z2  = { (_Float16)0.f, (_Float16)0.f };
    const h2 ns2 = { (_Float16)NEG, (_Float16)NEG };

    h2 xr2[8], at2[8];
    #pragma unroll
    for (int i = 0; i < 4; ++i) {
        float4 t4 = *(const float4*)&xr[(size_t)node * HC + c0 + i * 4];
        xr2[i*2+0] = h2{ (_Float16)t4.x, (_Float16)t4.y };
        xr2[i*2+1] = h2{ (_Float16)t4.z, (_Float16)t4.w };
        float4 a4 = *(const float4*)&att[c0 + i * 4];
        at2[i*2+0] = h2{ (_Float16)a4.x, (_Float16)a4.y };
        at2[i*2+1] = h2{ (_Float16)a4.z, (_Float16)a4.w };
    }
    h2 acc2[8];
    #pragma unroll
    for (int i = 0; i < 8; ++i) acc2[i] = z2;
    float denom = 0.f;

    auto load_edge = [&](int j, uint4& w0, uint4& w1) {
        const uint4* rp = (const uint4*)&xlh[(size_t)j * HC + c0];
        w0 = rp[0]; w1 = rp[1];
    };
    auto compute_edge = [&](uint4 w0, uint4 w1, bool valid) {
        h2 x2[8];
        x2[0] = __builtin_bit_cast(h2, w0.x); x2[1] = __builtin_bit_cast(h2, w0.y);
        x2[2] = __builtin_bit_cast(h2, w0.z); x2[3] = __builtin_bit_cast(h2, w0.w);
        x2[4] = __builtin_bit_cast(h2, w1.x); x2[5] = __builtin_bit_cast(h2, w1.y);
        x2[6] = __builtin_bit_cast(h2, w1.z); x2[7] = __builtin_bit_cast(h2, w1.w);
        h2 p2 = z2;
        #pragma unroll
        for (int i = 0; i < 8; ++i) {
            h2 g  = x2[i] + xr2[i];
            h2 gs = g * ns2;
            g = __builtin_elementwise_max(g, gs);   // leaky: max(g, 0.2g), exact
            p2 += g * at2[i];
        }
        float p = (float)p2.x + (float)p2.y;
        p += __shfl_xor(p, 1); p += __shfl_xor(p, 2);   // 4 lanes = one head
        float ex = valid ? __expf(p) : 0.f;             // logits O(1): no max shift
        denom += ex;
        h2 e2 = { (_Float16)ex, (_Float16)ex };
        #pragma unroll
        for (int i = 0; i < 8; ++i) acc2[i] += e2 * x2[i];
    };

    {   // self loop (counted once, slot 0)
        uint4 s0v, s1v;
        load_edge(node, s0v, s1v);
        compute_edge(s0v, s1v, sub == 0);
    }

    int s0 = offsets[node], s1 = offsets[node + 1];
    for (int base = s0; base < s1; base += 64) {
        int rem = s1 - base;
        int cnt = rem < 64 ? rem : 64;
        int jv = (base + lane < s1) ? ssrc[base + lane] : 0;
        int niter = (cnt + 3) >> 2;
        uint4 a0, a1, b0, b1;
        int jA = __shfl(jv, sub, 64);
        load_edge(jA, a0, a1);
        for (int it = 0; it < niter; it += 2) {
            int eB = ((it + 1) << 2) + sub;
            int jB = __shfl(jv, eB & 63, 64);
            load_edge(jB, b0, b1);                    // prefetch B under A's compute
            compute_edge(a0, a1, ((it << 2) + sub) < cnt);
            int eA2 = ((it + 2) << 2) + sub;
            int jA2 = __shfl(jv, eA2 & 63, 64);
            load_edge(jA2, a0, a1);                   // prefetch next A under B
            compute_edge(b0, b1, eB < cnt);
        }
    }

    // unpack to fp32, reduce over the 4 edge slots
    float accf[16];
    #pragma unroll
    for (int i = 0; i < 8; ++i) {
        accf[2*i]   = (float)acc2[i].x;
        accf[2*i+1] = (float)acc2[i].y;
    }
    #pragma unroll
    for (int i = 0; i < 16; ++i) {
        accf[i] += __shfl_xor(accf[i], 16);
        accf[i] += __shfl_xor(accf[i], 32);
    }
    denom += __shfl_xor(denom, 16);
    denom += __shfl_xor(denom, 32);

    float inv = 1.f / denom;
    if (sub == 0) {   // 16 lanes write 16 fp16 each
        float bcf[16];
        #pragma unroll
        for (int i = 0; i < 4; ++i) {
            float4 bc = *(const float4*)&b_conv[c0 + i * 4];
            bcf[i*4+0] = bc.x; bcf[i*4+1] = bc.y; bcf[i*4+2] = bc.z; bcf[i*4+3] = bc.w;
        }
        unsigned ww[8];
        #pragma unroll
        for (int i = 0; i < 8; ++i) {
            h2 p = { (_Float16)(accf[2*i]   * inv + bcf[2*i]),
                     (_Float16)(accf[2*i+1] * inv + bcf[2*i+1]) };
            ww[i] = __builtin_bit_cast(unsigned, p);
        }
        uint4 o0 = { ww[0], ww[1], ww[2], ww[3] };
        uint4 o1 = { ww[4], ww[5], ww[6], ww[7] };
        *(uint4*)&ovh[(size_t)node * HC + c0]     = o0;
        *(uint4*)&ovh[(size_t)node * HC + c0 + 8] = o1;
    }
}

// ---------------- post: relu(ov @ W_lin + b_lin) + h -> LayerNorm -> out -----

__global__ __launch_bounds__(256) void k_post(
    const unsigned short* __restrict__ ovh, const unsigned short* __restrict__ Wt16,
    const float* __restrict__ b_lin, const float* __restrict__ hbuf,
    const float* __restrict__ ln_w, const float* __restrict__ ln_b,
    float* __restrict__ out) {
    int t = threadIdx.x;
    int lane = t & 63, w = t >> 6;
    int node0 = blockIdx.x * 64 + w * 16;
    int r = lane & 15, kc = lane >> 4;
    int noder = node0 + r;
    int nodec = noder < N_NODES ? noder : N_NODES - 1;

    f32x4 acc[4] = {{0,0,0,0},{0,0,0,0},{0,0,0,0},{0,0,0,0}};
    #pragma unroll
    for (int k0 = 0; k0 < HC; k0 += 32) {
        int kb = k0 + kc * 8;
        f16x8 af = *(const f16x8*)&ovh[(size_t)nodec * HC + kb];
        #pragma unroll
        for (int cb = 0; cb < 4; ++cb) {
            f16x8 bf = *(const f16x8*)&Wt16[(size_t)(cb * 16 + r) * HC + kb];
            acc[cb] = __builtin_amdgcn_mfma_f32_16x16x32_f16(af, bf, acc[cb], 0, 0, 0);
        }
    }

    int ci = (lane >> 4) * 4, cj = lane & 15;
    #pragma unroll
    for (int rr = 0; rr < 4; ++rr) {
        int grow = node0 + ci + rr;
        int growc = grow < N_NODES ? grow : N_NODES - 1;
        float y[4];
        float ssum = 0.f;
        #pragma unroll
        for (int cb = 0; cb < 4; ++cb) {
            int col = cb * 16 + cj;
            float a = acc[cb][rr] + b_lin[col];
            a = a > 0.f ? a : 0.f;
            float yy = a + hbuf[(size_t)growc * C_OUT + col];
            y[cb] = yy;
            ssum += yy;
        }
        ssum += __shfl_xor(ssum, 1); ssum += __shfl_xor(ssum, 2);
        ssum += __shfl_xor(ssum, 4); ssum += __shfl_xor(ssum, 8);
        float m = ssum * (1.f / 64.f);
        float vs = 0.f;
        #pragma unroll
        for (int cb = 0; cb < 4; ++cb) { float d = y[cb] - m; vs += d * d; }
        vs += __shfl_xor(vs, 1); vs += __shfl_xor(vs, 2);
        vs += __shfl_xor(vs, 4); vs += __shfl_xor(vs, 8);
        float rinv = rsqrtf(vs * (1.f / 64.f) + 1e-12f);
        if (grow < N_NODES) {
            #pragma unroll
            for (int cb = 0; cb < 4; ++cb) {
                int col = cb * 16 + cj;
                out[(size_t)grow * C_OUT + col] =
                    ln_w[col] * (y[cb] - m) * rinv + ln_b[col];
            }
        }
    }
}

// ---------------- launch ----------------

extern "C" void kernel_launch(void* const* d_in, const int* in_sizes, int n_in,
                              void* d_out, int out_size, void* d_ws, size_t ws_size,
                              hipStream_t stream) {
    const float* x     = (const float*)d_in[0];
    const int*   ei    = (const int*)  d_in[1];
    const float* W_ae  = (const float*)d_in[2];
    const float* b_ae  = (const float*)d_in[3];
    const float* Wl    = (const float*)d_in[4];
    const float* bl    = (const float*)d_in[5];
    const float* Wr    = (const float*)d_in[6];
    const float* br    = (const float*)d_in[7];
    const float* att   = (const float*)d_in[8];
    const float* b_conv= (const float*)d_in[9];
    const float* W_lin = (const float*)d_in[10];
    const float* b_lin = (const float*)d_in[11];
    const float* ln_w  = (const float*)d_in[12];
    const float* ln_b  = (const float*)d_in[13];
    float* out = (float*)d_out;
    const int* src = ei;
    const int* dst = ei + N_EDGES;

    char* ws = (char*)d_ws;
    size_t off = 0;
    auto alloc = [&](size_t bytes) {
        void* p = ws + off;
        off = (off + bytes + 255) & ~(size_t)255;
        return p;
    };
    float* h       = (float*)alloc((size_t)N_NODES * C_OUT * 4);
    unsigned short* xlh = (unsigned short*)alloc((size_t)N_NODES * HC * 2);
    float* xr      = (float*)alloc((size_t)N_NODES * HC * 4);
    unsigned short* ovh = (unsigned short*)alloc((size_t)N_NODES * HC * 2);
    int*   counts  = (int*)  alloc((size_t)N_NODES * 4);
    int*   offsets = (int*)  alloc((size_t)(N_NODES + 1) * 4);
    int*   cursor  = (int*)  alloc((size_t)N_NODES * 4);
    int*   ssrc    = (int*)  alloc((size_t)N_EDGES * 4);
    unsigned short* Wpk  = (unsigned short*)alloc((size_t)C_OUT * KPAD * 2);
    unsigned short* Wt16 = (unsigned short*)alloc((size_t)C_OUT * HC * 2);
    int*   bsum    = (int*)  alloc((size_t)SCAN_B * 4);
    int*   bbase   = (int*)  alloc((size_t)SCAN_B * 4);

    (void)hipMemsetAsync(counts, 0, (size_t)N_NODES * 4, stream);
    k_prep   <<<576 + (N_EDGES + 255) / 256, 256, 0, stream>>>(W_ae, Wpk, W_lin, Wt16,
                                                               dst, counts);
    k_scan1  <<<SCAN_B, 256, 0, stream>>>(counts, bsum);
    k_scan2  <<<1, 64, 0, stream>>>(bsum, bbase, offsets);
    k_scan3  <<<SCAN_B, 256, 0, stream>>>(counts, bbase, offsets, cursor);
    k_gemm_sc<<<2500, 512, 0, stream>>>(x, Wpk, b_ae, h, src, dst, cursor, ssrc);
    k_xlxr2  <<<((N_NODES + 63) / 64) * 4, 256, 0, stream>>>(h, Wl, bl, Wr, br, xlh, xr);
    k_attn   <<<N_NODES / 4, 256, 0, stream>>>(xlh, xr, offsets, ssrc, att, b_conv, ovh);
    k_post   <<<(N_NODES + 63) / 64, 256, 0, stream>>>(ovh, Wt16, b_lin, h,
                                                       ln_w, ln_b, out);
}